// Round 1
// baseline (5998.596 us; speedup 1.0000x reference)
//
#include <hip/hip_runtime.h>
#include <math.h>

#define H 2048
#define IDIM 1408
#define NE 8
#define NTOK 8192
#define TWO_I 2816

// ---------------- workspace layout (bytes) ----------------
// [0..31]     int cnt[8]
// [64..95]    int offs[8]
// [1024..)    int bucket_idx[8][NTOK]
// then        float bucket_w[8][NTOK]
// then        float gate[NTOK]
// [1MB..)     float act[2*NTOK][IDIM]   (shared path uses rows 0..NTOK-1 first,
//                                        expert path reuses the region afterwards)
#define CNT_OFF  0
#define OFFS_OFF 64
#define BIDX_OFF 1024
#define BW_OFF   (BIDX_OFF + NE * NTOK * 4)
#define GATE_OFF (BW_OFF + NE * NTOK * 4)
#define ACT_OFF  (1u << 20)

// ---------------- small utility kernels ----------------
__global__ void zero_meta_kernel(int* p) {
    if (threadIdx.x < 16) p[threadIdx.x] = 0;   // cnt[8] + offs[8]
}

__global__ void prefix_kernel(const int* __restrict__ cnt, int* __restrict__ offs) {
    if (threadIdx.x == 0) {
        int s = 0;
        for (int e = 0; e < NE; e++) { offs[e] = s; s += cnt[e]; }
    }
}

// ---------------- router: logits, top-2 softmax, sigmoid gate, bucketing ----------------
__global__ __launch_bounds__(64)
void router_kernel(const float* __restrict__ x,
                   const float* __restrict__ w_router,   // [H][E]
                   const float* __restrict__ w_sgate,    // [H]
                   int* __restrict__ cnt,
                   int* __restrict__ bidx,
                   float* __restrict__ bw,
                   float* __restrict__ gate) {
    const int t = blockIdx.x;
    const int lane = threadIdx.x;
    const float* xr = x + (size_t)t * H;

    float acc[NE];
#pragma unroll
    for (int e = 0; e < NE; e++) acc[e] = 0.f;
    float accg = 0.f;

    for (int h = lane; h < H; h += 64) {
        float xv = xr[h];
        const float* wr = w_router + (size_t)h * NE;
#pragma unroll
        for (int e = 0; e < NE; e++) acc[e] += xv * wr[e];
        accg += xv * w_sgate[h];
    }
#pragma unroll
    for (int off = 32; off > 0; off >>= 1) {
#pragma unroll
        for (int e = 0; e < NE; e++) acc[e] += __shfl_down(acc[e], off, 64);
        accg += __shfl_down(accg, off, 64);
    }
    if (lane == 0) {
        // top-2 (ties -> lowest index, matches lax.top_k)
        int i0 = 0; float v0 = acc[0];
        for (int e = 1; e < NE; e++) if (acc[e] > v0) { v0 = acc[e]; i0 = e; }
        int i1 = -1; float v1 = -3.4e38f;
        for (int e = 0; e < NE; e++) if (e != i0 && acc[e] > v1) { v1 = acc[e]; i1 = e; }
        // softmax over the two selected logits (v0 >= v1)
        float e1 = expf(v1 - v0);
        float inv = 1.f / (1.f + e1);
        float p0 = inv;
        float p1 = e1 * inv;
        int pos0 = atomicAdd(&cnt[i0], 1);
        bidx[i0 * NTOK + pos0] = t; bw[i0 * NTOK + pos0] = p0;
        int pos1 = atomicAdd(&cnt[i1], 1);
        bidx[i1 * NTOK + pos1] = t; bw[i1 * NTOK + pos1] = p1;
        gate[t] = 1.f / (1.f + expf(-accg));
    }
}

// ---------------- gate_up GEMM with fused SwiGLU ----------------
// C tile: 128 rows x 64 cols (of I), dual accumulators for g (cols n) and u (cols n+I).
// act[row][n] = silu(g) * u
template <bool GATHER>
__global__ __launch_bounds__(256)
void gateup_kernel(const float* __restrict__ x,       // [NTOK][H]
                   const float* __restrict__ w,       // GATHER ? [E][H][2I] : [H][2I]
                   const int* __restrict__ cnt,
                   const int* __restrict__ offs,
                   const int* __restrict__ bidx,
                   const float* __restrict__ bw,
                   float* __restrict__ act) {
    const int e  = GATHER ? blockIdx.z : 0;
    const int m0 = blockIdx.y * 128;
    const int n0 = blockIdx.x * 64;
    int rows;
    if (GATHER) { rows = cnt[e]; if (m0 >= rows) return; }
    else        { rows = NTOK; }
    const float* W = w + (GATHER ? (size_t)e * H * TWO_I : 0);

    __shared__ float As[16][132];   // transposed A tile, padded
    __shared__ float Bg[16][68];
    __shared__ float Bu[16][68];

    const int tid = threadIdx.x;
    const int tx = tid & 15;    // 16 col-groups of 4
    const int ty = tid >> 4;    // 16 row-groups of 8

    float accg[8][4] = {{0.f}};
    float accu[8][4] = {{0.f}};

    // A staging: 128x16 floats = 512 float4; this thread handles f4 ids tid and tid+256
    const int ar0 = tid >> 2;
    const int ar1 = (tid >> 2) + 64;
    const int ak  = (tid & 3) << 2;
    int src0 = -1, src1 = -1; float wt0 = 0.f, wt1 = 0.f;
    {
        int gm0 = m0 + ar0, gm1 = m0 + ar1;
        if (GATHER) {
            if (gm0 < rows) { src0 = bidx[e * NTOK + gm0]; wt0 = bw[e * NTOK + gm0]; }
            if (gm1 < rows) { src1 = bidx[e * NTOK + gm1]; wt1 = bw[e * NTOK + gm1]; }
        } else {
            src0 = gm0; src1 = gm1; wt0 = 1.f; wt1 = 1.f;
        }
    }
    // B staging: per half 16x64 = 256 float4; k = tid/16, n = (tid%16)*4
    const int bk = tid >> 4;
    const int bn = (tid & 15) << 2;

    for (int k0 = 0; k0 < H; k0 += 16) {
        float4 a0 = make_float4(0.f, 0.f, 0.f, 0.f), a1 = a0;
        if (src0 >= 0) a0 = *(const float4*)(x + (size_t)src0 * H + k0 + ak);
        if (src1 >= 0) a1 = *(const float4*)(x + (size_t)src1 * H + k0 + ak);
        a0.x *= wt0; a0.y *= wt0; a0.z *= wt0; a0.w *= wt0;
        a1.x *= wt1; a1.y *= wt1; a1.z *= wt1; a1.w *= wt1;
        float4 bgv = *(const float4*)(W + (size_t)(k0 + bk) * TWO_I + n0 + bn);
        float4 buv = *(const float4*)(W + (size_t)(k0 + bk) * TWO_I + IDIM + n0 + bn);
        __syncthreads();
        As[ak + 0][ar0] = a0.x; As[ak + 1][ar0] = a0.y; As[ak + 2][ar0] = a0.z; As[ak + 3][ar0] = a0.w;
        As[ak + 0][ar1] = a1.x; As[ak + 1][ar1] = a1.y; As[ak + 2][ar1] = a1.z; As[ak + 3][ar1] = a1.w;
        *(float4*)&Bg[bk][bn] = bgv;
        *(float4*)&Bu[bk][bn] = buv;
        __syncthreads();
#pragma unroll
        for (int k = 0; k < 16; k++) {
            float a[8];
            *(float4*)&a[0] = *(const float4*)&As[k][ty * 8];
            *(float4*)&a[4] = *(const float4*)&As[k][ty * 8 + 4];
            float bg4[4], bu4[4];
            *(float4*)&bg4[0] = *(const float4*)&Bg[k][tx * 4];
            *(float4*)&bu4[0] = *(const float4*)&Bu[k][tx * 4];
#pragma unroll
            for (int i = 0; i < 8; i++) {
#pragma unroll
                for (int j = 0; j < 4; j++) {
                    accg[i][j] += a[i] * bg4[j];
                    accu[i][j] += a[i] * bu4[j];
                }
            }
        }
    }

    const int arow_base = GATHER ? offs[e] : 0;
#pragma unroll
    for (int i = 0; i < 8; i++) {
        int r = m0 + ty * 8 + i;
        if (r >= rows) continue;
        float4 o;
        float g, u;
        g = accg[i][0]; u = accu[i][0]; o.x = g / (1.f + expf(-g)) * u;
        g = accg[i][1]; u = accu[i][1]; o.y = g / (1.f + expf(-g)) * u;
        g = accg[i][2]; u = accu[i][2]; o.z = g / (1.f + expf(-g)) * u;
        g = accg[i][3]; u = accu[i][3]; o.w = g / (1.f + expf(-g)) * u;
        *(float4*)(act + (size_t)(arow_base + r) * IDIM + n0 + tx * 4) = o;
    }
}

// ---------------- down GEMM ----------------
// SCATTER=false: out[t][n] = gate[t] * (act[t] @ w_shared_down)[n]   (plain store)
// SCATTER=true : atomicAdd(out[token][n], (act[offs[e]+r] @ w_down[e])[n])
template <bool SCATTER>
__global__ __launch_bounds__(256)
void down_kernel(const float* __restrict__ act,
                 const float* __restrict__ w,     // SCATTER ? [E][I][H] : [I][H]
                 const int* __restrict__ cnt,
                 const int* __restrict__ offs,
                 const int* __restrict__ bidx,
                 const float* __restrict__ gate,
                 float* __restrict__ out) {
    const int e  = SCATTER ? blockIdx.z : 0;
    const int m0 = blockIdx.y * 128;
    const int n0 = blockIdx.x * 128;
    int rows;
    if (SCATTER) { rows = cnt[e]; if (m0 >= rows) return; }
    else         { rows = NTOK; }
    const float* W = w + (SCATTER ? (size_t)e * IDIM * H : 0);
    const float* A = act + (size_t)(SCATTER ? offs[e] : 0) * IDIM;

    __shared__ float As[16][132];
    __shared__ float Bs[16][132];

    const int tid = threadIdx.x;
    const int tx = tid & 15;    // 16 col-groups of 8
    const int ty = tid >> 4;    // 16 row-groups of 8

    float acc[8][8] = {{0.f}};

    const int ar0 = tid >> 2;
    const int ar1 = (tid >> 2) + 64;
    const int ak  = (tid & 3) << 2;
    const int gm0 = m0 + ar0, gm1 = m0 + ar1;
    // B staging: 16x128 = 512 float4; ids tid, tid+256: k = id/32, n = (id%32)*4
    const int bk0 = tid >> 5;
    const int bk1 = (tid >> 5) + 8;
    const int bn  = (tid & 31) << 2;

    for (int k0 = 0; k0 < IDIM; k0 += 16) {
        float4 a0 = make_float4(0.f, 0.f, 0.f, 0.f), a1 = a0;
        if (gm0 < rows) a0 = *(const float4*)(A + (size_t)gm0 * IDIM + k0 + ak);
        if (gm1 < rows) a1 = *(const float4*)(A + (size_t)gm1 * IDIM + k0 + ak);
        float4 b0 = *(const float4*)(W + (size_t)(k0 + bk0) * H + n0 + bn);
        float4 b1 = *(const float4*)(W + (size_t)(k0 + bk1) * H + n0 + bn);
        __syncthreads();
        As[ak + 0][ar0] = a0.x; As[ak + 1][ar0] = a0.y; As[ak + 2][ar0] = a0.z; As[ak + 3][ar0] = a0.w;
        As[ak + 0][ar1] = a1.x; As[ak + 1][ar1] = a1.y; As[ak + 2][ar1] = a1.z; As[ak + 3][ar1] = a1.w;
        *(float4*)&Bs[bk0][bn] = b0;
        *(float4*)&Bs[bk1][bn] = b1;
        __syncthreads();
#pragma unroll
        for (int k = 0; k < 16; k++) {
            float a[8], b[8];
            *(float4*)&a[0] = *(const float4*)&As[k][ty * 8];
            *(float4*)&a[4] = *(const float4*)&As[k][ty * 8 + 4];
            *(float4*)&b[0] = *(const float4*)&Bs[k][tx * 8];
            *(float4*)&b[4] = *(const float4*)&Bs[k][tx * 8 + 4];
#pragma unroll
            for (int i = 0; i < 8; i++)
#pragma unroll
                for (int j = 0; j < 8; j++) acc[i][j] += a[i] * b[j];
        }
    }

#pragma unroll
    for (int i = 0; i < 8; i++) {
        int r = m0 + ty * 8 + i;
        if (r >= rows) continue;
        if (SCATTER) {
            int token = bidx[e * NTOK + r];
            float* orow = out + (size_t)token * H + n0 + tx * 8;
#pragma unroll
            for (int j = 0; j < 8; j++) atomicAdd(&orow[j], acc[i][j]);
        } else {
            float gv = gate[r];
            float4 o0, o1;
            o0.x = gv * acc[i][0]; o0.y = gv * acc[i][1]; o0.z = gv * acc[i][2]; o0.w = gv * acc[i][3];
            o1.x = gv * acc[i][4]; o1.y = gv * acc[i][5]; o1.z = gv * acc[i][6]; o1.w = gv * acc[i][7];
            float* orow = out + (size_t)r * H + n0 + tx * 8;
            *(float4*)&orow[0] = o0;
            *(float4*)&orow[4] = o1;
        }
    }
}

// ---------------- launch ----------------
extern "C" void kernel_launch(void* const* d_in, const int* in_sizes, int n_in,
                              void* d_out, int out_size, void* d_ws, size_t ws_size,
                              hipStream_t stream) {
    const float* x     = (const float*)d_in[0];
    const float* w_rt  = (const float*)d_in[1];
    const float* w_gu  = (const float*)d_in[2];
    const float* w_dn  = (const float*)d_in[3];
    const float* w_sgu = (const float*)d_in[4];
    const float* w_sdn = (const float*)d_in[5];
    const float* w_sg  = (const float*)d_in[6];
    float* out = (float*)d_out;

    char* ws = (char*)d_ws;
    int*   cnt  = (int*)(ws + CNT_OFF);
    int*   offs = (int*)(ws + OFFS_OFF);
    int*   bidx = (int*)(ws + BIDX_OFF);
    float* bw   = (float*)(ws + BW_OFF);
    float* gate = (float*)(ws + GATE_OFF);
    float* act  = (float*)(ws + ACT_OFF);

    zero_meta_kernel<<<1, 64, 0, stream>>>(cnt);
    router_kernel<<<NTOK, 64, 0, stream>>>(x, w_rt, w_sg, cnt, bidx, bw, gate);
    prefix_kernel<<<1, 64, 0, stream>>>(cnt, offs);

    // shared expert: act rows 0..NTOK-1
    {
        dim3 g(IDIM / 64, NTOK / 128, 1);
        gateup_kernel<false><<<g, 256, 0, stream>>>(x, w_sgu, cnt, offs, bidx, bw, act);
    }
    {
        dim3 g(H / 128, NTOK / 128, 1);
        down_kernel<false><<<g, 256, 0, stream>>>(act, w_sdn, cnt, offs, bidx, gate, out);
    }
    // routed experts (act region reused; stream-ordered after shared down)
    {
        dim3 g(IDIM / 64, NTOK / 128, NE);
        gateup_kernel<true><<<g, 256, 0, stream>>>(x, w_gu, cnt, offs, bidx, bw, act);
    }
    {
        dim3 g(H / 128, NTOK / 128, NE);
        down_kernel<true><<<g, 256, 0, stream>>>(act, w_dn, cnt, offs, bidx, gate, out);
    }
}

// Round 2
// 1429.264 us; speedup vs baseline: 4.1970x; 4.1970x over previous
//
#include <hip/hip_runtime.h>
#include <math.h>

#define H 2048
#define IDIM 1408
#define TWO_I 2816
#define NE 8
#define NTOK 8192
#define BK 32
#define LDA 40   // padded LDS row stride (bf16 elems): 80B, breaks pow2 banks, keeps 16B align

typedef float f32x4 __attribute__((ext_vector_type(4)));
typedef short bf16x8 __attribute__((ext_vector_type(8)));

// ---------------- workspace layout (bytes) ----------------
#define CNT_OFF   0
#define OFFS_OFF  64
#define BIDX_OFF  1024
#define BW_OFF    (BIDX_OFF + NE*NTOK*4)
#define GATE_OFF  (BW_OFF + NE*NTOK*4)
#define XS_OFF    ((size_t)1 << 20)
#define XS_ROWS   (NTOK + 2*NTOK)                     // 8192 unscaled + 16384 gathered*scaled
#define WGU_OFF   (XS_OFF  + (size_t)XS_ROWS*H*2)     // bf16 [E][2I][H]
#define WDN_OFF   (WGU_OFF + (size_t)NE*TWO_I*H*2)    // bf16 [E][H][I]
#define WSGU_OFF  (WDN_OFF + (size_t)NE*H*IDIM*2)     // bf16 [2I][H]
#define WSDN_OFF  (WSGU_OFF + (size_t)TWO_I*H*2)      // bf16 [H][I]
#define ACT_OFF   (WSDN_OFF + (size_t)H*IDIM*2)       // bf16 [16384][I]

__device__ inline ushort f2bf(float f) {
    union { float f; uint u; } v; v.f = f;
    uint u = v.u;
    uint r = u + 0x7fffu + ((u >> 16) & 1u);   // RNE
    return (ushort)(r >> 16);
}

// ---------------- small utility kernels ----------------
__global__ void zero_meta_kernel(int* p) {
    if (threadIdx.x < 16) p[threadIdx.x] = 0;
}

__global__ void prefix_kernel(const int* __restrict__ cnt, int* __restrict__ offs) {
    if (threadIdx.x == 0) {
        int s = 0;
        for (int e = 0; e < NE; e++) { offs[e] = s; s += cnt[e]; }
    }
}

// ---------------- router ----------------
__global__ __launch_bounds__(64)
void router_kernel(const float* __restrict__ x,
                   const float* __restrict__ w_router,
                   const float* __restrict__ w_sgate,
                   int* __restrict__ cnt,
                   int* __restrict__ bidx,
                   float* __restrict__ bw,
                   float* __restrict__ gate) {
    const int t = blockIdx.x;
    const int lane = threadIdx.x;
    const float* xr = x + (size_t)t * H;

    float acc[NE];
#pragma unroll
    for (int e = 0; e < NE; e++) acc[e] = 0.f;
    float accg = 0.f;

    for (int h = lane; h < H; h += 64) {
        float xv = xr[h];
        const float* wr = w_router + (size_t)h * NE;
#pragma unroll
        for (int e = 0; e < NE; e++) acc[e] += xv * wr[e];
        accg += xv * w_sgate[h];
    }
#pragma unroll
    for (int off = 32; off > 0; off >>= 1) {
#pragma unroll
        for (int e = 0; e < NE; e++) acc[e] += __shfl_down(acc[e], off, 64);
        accg += __shfl_down(accg, off, 64);
    }
    if (lane == 0) {
        int i0 = 0; float v0 = acc[0];
        for (int e = 1; e < NE; e++) if (acc[e] > v0) { v0 = acc[e]; i0 = e; }
        int i1 = -1; float v1 = -3.4e38f;
        for (int e = 0; e < NE; e++) if (e != i0 && acc[e] > v1) { v1 = acc[e]; i1 = e; }
        float e1 = expf(v1 - v0);
        float inv = 1.f / (1.f + e1);
        int pos0 = atomicAdd(&cnt[i0], 1);
        bidx[i0 * NTOK + pos0] = t; bw[i0 * NTOK + pos0] = inv;
        int pos1 = atomicAdd(&cnt[i1], 1);
        bidx[i1 * NTOK + pos1] = t; bw[i1 * NTOK + pos1] = e1 * inv;
        gate[t] = 1.f / (1.f + expf(-accg));
    }
}

// ---------------- transpose + fp32->bf16 convert:  dst[c][r] = bf16(src[r][c]) ----------------
__global__ __launch_bounds__(256)
void transpose_cvt(const float* __restrict__ src, ushort* __restrict__ dst, int R, int C) {
    const size_t bs = (size_t)R * C;
    src += (size_t)blockIdx.z * bs;
    dst += (size_t)blockIdx.z * bs;
    const int c0 = blockIdx.x * 64, r0 = blockIdx.y * 64;
    __shared__ float t[64][65];
    const int tid = threadIdx.x;
#pragma unroll
    for (int p = 0; p < 4; p++) {
        int id = tid + p * 256;
        int r = id >> 4, c4 = (id & 15) * 4;
        float4 v = *(const float4*)(src + (size_t)(r0 + r) * C + c0 + c4);
        t[r][c4 + 0] = v.x; t[r][c4 + 1] = v.y; t[r][c4 + 2] = v.z; t[r][c4 + 3] = v.w;
    }
    __syncthreads();
#pragma unroll
    for (int p = 0; p < 4; p++) {
        int id = tid + p * 256;
        int c = id >> 4, r4 = (id & 15) * 4;
        union { ushort us[4]; uint2 v; } o;
#pragma unroll
        for (int q = 0; q < 4; q++) o.us[q] = f2bf(t[r4 + q][c]);
        *(uint2*)(dst + (size_t)(c0 + c) * R + r0 + r4) = o.v;
    }
}

// ---------------- x prep: bf16 convert; gathered + routing-weight scaled copies ----------------
// xs rows [0,8192): bf16(x) unscaled (shared expert A)
// xs rows [8192+offs[e]+r): bf16(x[bidx]*bw)  (expert A, bucket order)
__global__ __launch_bounds__(256)
void xprep_kernel(const float* __restrict__ x, const int* __restrict__ cnt,
                  const int* __restrict__ offs, const int* __restrict__ bidx,
                  const float* __restrict__ bw, ushort* __restrict__ xs) {
    const int y = blockIdx.y;
    const int r = blockIdx.x;
    int srow, drow; float wt;
    if (y == 0) { srow = r; drow = r; wt = 1.f; }
    else {
        int e = y - 1;
        if (r >= cnt[e]) return;
        srow = bidx[e * NTOK + r]; wt = bw[e * NTOK + r];
        drow = NTOK + offs[e] + r;
    }
    const int tid = threadIdx.x;
    const float* sp = x + (size_t)srow * H + tid * 8;
    float4 v0 = *(const float4*)sp;
    float4 v1 = *(const float4*)(sp + 4);
    union { ushort us[8]; uint4 v; } o;
    o.us[0] = f2bf(v0.x * wt); o.us[1] = f2bf(v0.y * wt);
    o.us[2] = f2bf(v0.z * wt); o.us[3] = f2bf(v0.w * wt);
    o.us[4] = f2bf(v1.x * wt); o.us[5] = f2bf(v1.y * wt);
    o.us[6] = f2bf(v1.z * wt); o.us[7] = f2bf(v1.w * wt);
    *(uint4*)(xs + (size_t)drow * H + tid * 8) = o.v;
}

// ---------------- gate_up MFMA GEMM with fused SwiGLU ----------------
// C tile 128(m) x 64(n of I); dual acc for gate (rows n of W^T) and up (rows I+n).
// act[obase+row][n] = bf16(silu(g)*u)
template <bool GATHER>
__global__ __launch_bounds__(256)
void gateup_mfma(const ushort* __restrict__ xs,
                 const ushort* __restrict__ wt,   // bf16 [E?][2I][H]
                 const int* __restrict__ cnt,
                 const int* __restrict__ offs,
                 ushort* __restrict__ act) {
    const int e = GATHER ? blockIdx.z : 0;
    const int rows = GATHER ? cnt[e] : NTOK;
    const int m0 = blockIdx.y * 128;
    if (GATHER && m0 >= rows) return;
    const int n0 = blockIdx.x * 64;
    const ushort* W = wt + (GATHER ? (size_t)e * TWO_I * H : 0);
    const int abase = GATHER ? (NTOK + offs[e]) : 0;
    const int obase = GATHER ? offs[e] : 0;

    __shared__ __align__(16) ushort As[128 * LDA];
    __shared__ __align__(16) ushort Bg[64 * LDA];
    __shared__ __align__(16) ushort Bu[64 * LDA];

    const int tid = threadIdx.x;
    const int wave = tid >> 6, lane = tid & 63;
    const int wm = (wave >> 1) * 64, wn = (wave & 1) * 32;
    const int quad = lane >> 4, l16 = lane & 15;

    const int srow = tid >> 2;          // 0..63
    const int skc  = (tid & 3) * 8;     // 0,8,16,24
    const int ar0 = srow, ar1 = srow + 64;
    const bool ok0 = (m0 + ar0) < rows;
    const bool ok1 = (m0 + ar1) < rows;
    const ushort* a0p = xs + (size_t)(abase + m0 + ar0) * H + skc;
    const ushort* a1p = xs + (size_t)(abase + m0 + ar1) * H + skc;
    const ushort* bgp = W + (size_t)(n0 + srow) * H + skc;
    const ushort* bup = W + (size_t)(IDIM + n0 + srow) * H + skc;

    f32x4 accg[4][2], accu[4][2];
#pragma unroll
    for (int i = 0; i < 4; i++)
#pragma unroll
        for (int j = 0; j < 2; j++) { accg[i][j] = (f32x4)0.f; accu[i][j] = (f32x4)0.f; }

    for (int k0 = 0; k0 < H; k0 += BK) {
        uint4 av0 = ok0 ? *(const uint4*)(a0p + k0) : make_uint4(0, 0, 0, 0);
        uint4 av1 = ok1 ? *(const uint4*)(a1p + k0) : make_uint4(0, 0, 0, 0);
        uint4 bgv = *(const uint4*)(bgp + k0);
        uint4 buv = *(const uint4*)(bup + k0);
        __syncthreads();
        *(uint4*)&As[ar0 * LDA + skc] = av0;
        *(uint4*)&As[ar1 * LDA + skc] = av1;
        *(uint4*)&Bg[srow * LDA + skc] = bgv;
        *(uint4*)&Bu[srow * LDA + skc] = buv;
        __syncthreads();
        bf16x8 af[4], bgf[2], buf[2];
#pragma unroll
        for (int i = 0; i < 4; i++)
            af[i] = *(const bf16x8*)&As[(wm + i * 16 + l16) * LDA + quad * 8];
#pragma unroll
        for (int j = 0; j < 2; j++) {
            bgf[j] = *(const bf16x8*)&Bg[(wn + j * 16 + l16) * LDA + quad * 8];
            buf[j] = *(const bf16x8*)&Bu[(wn + j * 16 + l16) * LDA + quad * 8];
        }
#pragma unroll
        for (int i = 0; i < 4; i++)
#pragma unroll
            for (int j = 0; j < 2; j++) {
                accg[i][j] = __builtin_amdgcn_mfma_f32_16x16x32_bf16(af[i], bgf[j], accg[i][j], 0, 0, 0);
                accu[i][j] = __builtin_amdgcn_mfma_f32_16x16x32_bf16(af[i], buf[j], accu[i][j], 0, 0, 0);
            }
    }

#pragma unroll
    for (int i = 0; i < 4; i++) {
#pragma unroll
        for (int r = 0; r < 4; r++) {
            int row = m0 + wm + i * 16 + quad * 4 + r;
            if (row >= rows) continue;
            ushort* orow = act + (size_t)(obase + row) * IDIM + n0 + wn + l16;
#pragma unroll
            for (int j = 0; j < 2; j++) {
                float g = accg[i][j][r], u = accu[i][j][r];
                float v = g / (1.f + expf(-g)) * u;
                orow[j * 16] = f2bf(v);
            }
        }
    }
}

// ---------------- down MFMA GEMM ----------------
// SCATTER=false: out[row][n] = gate[row] * dot ; SCATTER=true: atomicAdd(out[token][n], dot)
template <bool SCATTER>
__global__ __launch_bounds__(256)
void down_mfma(const ushort* __restrict__ act,
               const ushort* __restrict__ wt,    // bf16 [E?][H][I]
               const int* __restrict__ cnt,
               const int* __restrict__ offs,
               const int* __restrict__ bidx,
               const float* __restrict__ gate,
               float* __restrict__ out) {
    const int e = SCATTER ? blockIdx.z : 0;
    const int rows = SCATTER ? cnt[e] : NTOK;
    const int m0 = blockIdx.y * 128;
    if (SCATTER && m0 >= rows) return;
    const int n0 = blockIdx.x * 128;
    const ushort* W = wt + (SCATTER ? (size_t)e * H * IDIM : 0);
    const ushort* A = act + (size_t)(SCATTER ? offs[e] : 0) * IDIM;

    __shared__ __align__(16) ushort As[128 * LDA];
    __shared__ __align__(16) ushort Bs[128 * LDA];

    const int tid = threadIdx.x;
    const int wave = tid >> 6, lane = tid & 63;
    const int wm = (wave >> 1) * 64, wn = (wave & 1) * 64;
    const int quad = lane >> 4, l16 = lane & 15;

    const int srow = tid >> 2;
    const int skc = (tid & 3) * 8;
    const int ar0 = srow, ar1 = srow + 64;
    const bool ok0 = (m0 + ar0) < rows, ok1 = (m0 + ar1) < rows;
    const ushort* a0p = A + (size_t)(m0 + ar0) * IDIM + skc;
    const ushort* a1p = A + (size_t)(m0 + ar1) * IDIM + skc;
    const ushort* b0p = W + (size_t)(n0 + ar0) * IDIM + skc;
    const ushort* b1p = W + (size_t)(n0 + ar1) * IDIM + skc;

    f32x4 acc[4][4];
#pragma unroll
    for (int i = 0; i < 4; i++)
#pragma unroll
        for (int j = 0; j < 4; j++) acc[i][j] = (f32x4)0.f;

    for (int k0 = 0; k0 < IDIM; k0 += BK) {
        uint4 av0 = ok0 ? *(const uint4*)(a0p + k0) : make_uint4(0, 0, 0, 0);
        uint4 av1 = ok1 ? *(const uint4*)(a1p + k0) : make_uint4(0, 0, 0, 0);
        uint4 bv0 = *(const uint4*)(b0p + k0);
        uint4 bv1 = *(const uint4*)(b1p + k0);
        __syncthreads();
        *(uint4*)&As[ar0 * LDA + skc] = av0;
        *(uint4*)&As[ar1 * LDA + skc] = av1;
        *(uint4*)&Bs[ar0 * LDA + skc] = bv0;
        *(uint4*)&Bs[ar1 * LDA + skc] = bv1;
        __syncthreads();
        bf16x8 af[4], bf[4];
#pragma unroll
        for (int i = 0; i < 4; i++)
            af[i] = *(const bf16x8*)&As[(wm + i * 16 + l16) * LDA + quad * 8];
#pragma unroll
        for (int j = 0; j < 4; j++)
            bf[j] = *(const bf16x8*)&Bs[(wn + j * 16 + l16) * LDA + quad * 8];
#pragma unroll
        for (int i = 0; i < 4; i++)
#pragma unroll
            for (int j = 0; j < 4; j++)
                acc[i][j] = __builtin_amdgcn_mfma_f32_16x16x32_bf16(af[i], bf[j], acc[i][j], 0, 0, 0);
    }

#pragma unroll
    for (int i = 0; i < 4; i++) {
#pragma unroll
        for (int r = 0; r < 4; r++) {
            int row = m0 + wm + i * 16 + quad * 4 + r;
            if (row >= rows) continue;
            if (SCATTER) {
                int token = bidx[e * NTOK + row];
                float* orow = out + (size_t)token * H + n0 + wn + l16;
#pragma unroll
                for (int j = 0; j < 4; j++) atomicAdd(&orow[j * 16], acc[i][j][r]);
            } else {
                float gv = gate[row];
                float* orow = out + (size_t)row * H + n0 + wn + l16;
#pragma unroll
                for (int j = 0; j < 4; j++) orow[j * 16] = gv * acc[i][j][r];
            }
        }
    }
}

// ---------------- launch ----------------
extern "C" void kernel_launch(void* const* d_in, const int* in_sizes, int n_in,
                              void* d_out, int out_size, void* d_ws, size_t ws_size,
                              hipStream_t stream) {
    const float* x     = (const float*)d_in[0];
    const float* w_rt  = (const float*)d_in[1];
    const float* w_gu  = (const float*)d_in[2];
    const float* w_dn  = (const float*)d_in[3];
    const float* w_sgu = (const float*)d_in[4];
    const float* w_sdn = (const float*)d_in[5];
    const float* w_sg  = (const float*)d_in[6];
    float* out = (float*)d_out;

    char* ws = (char*)d_ws;
    int*    cnt   = (int*)(ws + CNT_OFF);
    int*    offs  = (int*)(ws + OFFS_OFF);
    int*    bidx  = (int*)(ws + BIDX_OFF);
    float*  bw    = (float*)(ws + BW_OFF);
    float*  gate  = (float*)(ws + GATE_OFF);
    ushort* xs    = (ushort*)(ws + XS_OFF);
    ushort* wgu_t = (ushort*)(ws + WGU_OFF);
    ushort* wdn_t = (ushort*)(ws + WDN_OFF);
    ushort* wsgu_t= (ushort*)(ws + WSGU_OFF);
    ushort* wsdn_t= (ushort*)(ws + WSDN_OFF);
    ushort* act   = (ushort*)(ws + ACT_OFF);

    zero_meta_kernel<<<1, 64, 0, stream>>>(cnt);
    router_kernel<<<NTOK, 64, 0, stream>>>(x, w_rt, w_sg, cnt, bidx, bw, gate);
    prefix_kernel<<<1, 64, 0, stream>>>(cnt, offs);

    // weight transpose+convert: [R][C] fp32 -> [C][R] bf16
    transpose_cvt<<<dim3(TWO_I / 64, H / 64, NE), 256, 0, stream>>>(w_gu, wgu_t, H, TWO_I);
    transpose_cvt<<<dim3(H / 64, IDIM / 64, NE), 256, 0, stream>>>(w_dn, wdn_t, IDIM, H);
    transpose_cvt<<<dim3(TWO_I / 64, H / 64, 1), 256, 0, stream>>>(w_sgu, wsgu_t, H, TWO_I);
    transpose_cvt<<<dim3(H / 64, IDIM / 64, 1), 256, 0, stream>>>(w_sdn, wsdn_t, IDIM, H);

    // x -> bf16 (unscaled + gathered*scaled bucket copies)
    xprep_kernel<<<dim3(NTOK, NE + 1), 256, 0, stream>>>(x, cnt, offs, bidx, bw, xs);

    // shared expert
    gateup_mfma<false><<<dim3(IDIM / 64, NTOK / 128), 256, 0, stream>>>(xs, wsgu_t, cnt, offs, act);
    down_mfma<false><<<dim3(H / 128, NTOK / 128), 256, 0, stream>>>(act, wsdn_t, cnt, offs, bidx, gate, out);

    // routed experts
    gateup_mfma<true><<<dim3(IDIM / 64, NTOK / 128, NE), 256, 0, stream>>>(xs, wgu_t, cnt, offs, act);
    down_mfma<true><<<dim3(H / 128, NTOK / 128, NE), 256, 0, stream>>>(act, wdn_t, cnt, offs, bidx, gate, out);
}